// Round 8
// baseline (97.158 us; speedup 1.0000x reference)
//
#include <hip/hip_runtime.h>

#define NL 12
#define NB 2
#define NS 2048
#define ND 1024
#define NDK 256
#define NBS (NB*NS)   // 4096

typedef __attribute__((ext_vector_type(8))) short short8;
typedef __attribute__((ext_vector_type(4))) short short4v;
typedef __attribute__((ext_vector_type(4))) float floatx4;

__device__ __forceinline__ unsigned short f2bf(float f) {
    unsigned int u = __float_as_uint(f);
    u += 0x7FFFu + ((u >> 16) & 1u);
    return (unsigned short)(u >> 16);
}
__device__ __forceinline__ short f2bfs(float f) { return (short)f2bf(f); }
__device__ __forceinline__ float bf2f(short s) {
    return __uint_as_float(((unsigned int)(unsigned short)s) << 16);
}

// K1: W2t[d][d'] = sum_k Wk[k][d]*Wq[k][d']  (bf16 out, MFMA). 256 blocks.
__global__ void k_prep(const float* __restrict__ Wq, const float* __restrict__ Wk,
                       unsigned short* __restrict__ W2t) {
    const int tid = threadIdx.x;
    const int lane = tid & 63, wv = tid >> 6;
    const int wid = blockIdx.x * 4 + wv;      // 0..1023
    const int tm = wid >> 4;                  // d-tile (rows of W2t), 0..63
    const int tnb = wid & 15;                 // d'-tile (cols, 64 wide), 0..15
    const int lr = lane & 15, kh = lane >> 4;
    floatx4 acc[4];
#pragma unroll
    for (int c = 0; c < 4; ++c) acc[c] = (floatx4){0.f, 0.f, 0.f, 0.f};
#pragma unroll 2
    for (int kb = 0; kb < 8; ++kb) {
        const float* Ab = Wk + (size_t)(kb * 32 + kh * 8) * ND + tm * 16 + lr;
        const float* Bb = Wq + (size_t)(kb * 32 + kh * 8) * ND + tnb * 64 + lr;
        short8 a;
#pragma unroll
        for (int j = 0; j < 8; ++j) a[j] = f2bfs(Ab[(size_t)j * ND]);
#pragma unroll
        for (int c = 0; c < 4; ++c) {
            short8 b;
#pragma unroll
            for (int j = 0; j < 8; ++j) b[j] = f2bfs(Bb[(size_t)j * ND + c * 16]);
            acc[c] = __builtin_amdgcn_mfma_f32_16x16x32_bf16(a, b, acc[c], 0, 0, 0);
        }
    }
#pragma unroll
    for (int c = 0; c < 4; ++c)
#pragma unroll
        for (int r = 0; r < 4; ++r)
            W2t[(size_t)(tm * 16 + kh * 4 + r) * ND + tnb * 64 + c * 16 + lr] = f2bf(acc[c][r]);
}

// K2: LN-folded GEMM on raw fp32 x11 (w folded into A-fragments at staging; row
// stats accumulated fp32 from the same registers). Writes V' = rstd*y (bf16),
// alpha[p] = mu*rstd. Blocks >= 512: aux row-dots c1v = W2t.w, c2v = W2t.b.
// K3 later reconstructs v = V' + c2v - alpha*c1v.
#define BM 64
#define BN 128
#define BK 64
#define LDP 72    // padded LDS row (elements)
#define TLP 132   // padded epilogue row (elements)
__global__ __launch_bounds__(256) void k_vgemm(const float* __restrict__ x11,
                                               const unsigned short* __restrict__ W2t,
                                               const float* __restrict__ lnw,
                                               const float* __restrict__ lnb,
                                               unsigned short* __restrict__ V,
                                               float* __restrict__ alpha,
                                               float* __restrict__ c1v,
                                               float* __restrict__ c2v) {
    const int bid = blockIdx.x;
    if (bid >= 512) {            // aux: contiguous per-thread row dots (L2-hot W2t)
        const int t = threadIdx.x;
        if (t < 128) {
            const int row = (bid - 512) * 128 + t;
            const short8* wr = (const short8*)(W2t + (size_t)row * ND);
            const float4* w4 = (const float4*)lnw;
            const float4* b4 = (const float4*)lnb;
            float s1 = 0.f, s2 = 0.f;
#pragma unroll 4
            for (int i = 0; i < 128; ++i) {
                short8 m = wr[i];
                float4 wa = w4[2*i], wb = w4[2*i+1];
                float4 ba = b4[2*i], bb = b4[2*i+1];
                s1 += bf2f(m[0])*wa.x + bf2f(m[1])*wa.y + bf2f(m[2])*wa.z + bf2f(m[3])*wa.w
                    + bf2f(m[4])*wb.x + bf2f(m[5])*wb.y + bf2f(m[6])*wb.z + bf2f(m[7])*wb.w;
                s2 += bf2f(m[0])*ba.x + bf2f(m[1])*ba.y + bf2f(m[2])*ba.z + bf2f(m[3])*ba.w
                    + bf2f(m[4])*bb.x + bf2f(m[5])*bb.y + bf2f(m[6])*bb.z + bf2f(m[7])*bb.w;
            }
            c1v[row] = s1; c2v[row] = s2;
        }
        return;
    }
    __shared__ unsigned short As[2][BM * LDP];   // 18.4 KB
    __shared__ unsigned short Bs[2][BN * LDP];   // 36.9 KB
    __shared__ float s_s1[BM], s_s2[BM], s_rs[BM];
    const int tid = threadIdx.x;
    const int lane = tid & 63;
    const int wv = tid >> 6;
    const int wr = wv >> 1, wc = wv & 1;
    const int lr = lane & 15, kh = lane >> 4;
    // XCD swizzle: all 8 bn-blocks of one bm land on one XCD (bid%8 round-robin)
    const int bm0 = ((bid & 7) + 8 * ((bid >> 3) & 7)) * BM;
    const int bn0 = (bid >> 6) * BN;

    // A staging: 64x64 fp32 tile = 1024 float4, 4/thread (convert to bf16*w)
    int aRow[4], aC4[4], aOff[4];
    const float4* gAx[4];
#pragma unroll
    for (int j = 0; j < 4; ++j) {
        int idx = j * 256 + tid;
        aRow[j] = idx >> 4;
        aC4[j]  = idx & 15;
        aOff[j] = aRow[j] * LDP + aC4[j] * 4;
        gAx[j] = (const float4*)(x11 + (size_t)(bm0 + aRow[j]) * ND) + aC4[j];
    }
    // B staging: 128x64 bf16 tile = 1024 short8, 4/thread
    int bOff[4];
    const short8* gB[4];
#pragma unroll
    for (int j = 0; j < 4; ++j) {
        int idx = j * 256 + tid;
        int row = idx >> 3, c8 = idx & 7;
        bOff[j] = row * LDP + c8 * 8;
        gB[j] = (const short8*)(W2t + (size_t)(bn0 + row) * ND) + c8;
    }

    floatx4 acc[2][4];
#pragma unroll
    for (int m = 0; m < 2; ++m)
#pragma unroll
        for (int n = 0; n < 4; ++n) acc[m][n] = (floatx4){0.f, 0.f, 0.f, 0.f};

    float sa1[4], sa2[4];
#pragma unroll
    for (int j = 0; j < 4; ++j) { sa1[j] = 0.f; sa2[j] = 0.f; }

    float4 rax[4];
    short8 rb[4];
#pragma unroll
    for (int j = 0; j < 4; ++j) rax[j] = gAx[j][0];
#pragma unroll
    for (int j = 0; j < 4; ++j) rb[j] = gB[j][0];

    const float4* lnw4 = (const float4*)lnw;
    const int NT = ND / BK;   // 16
#pragma unroll 1
    for (int t = 0; t < NT; ++t) {
        unsigned short* Ab = As[t & 1];
        unsigned short* Bb = Bs[t & 1];
#pragma unroll
        for (int j = 0; j < 4; ++j) {
            float4 r = rax[j];
            sa1[j] += r.x + r.y + r.z + r.w;                       // raw-x stats
            sa2[j] += r.x*r.x + r.y*r.y + r.z*r.z + r.w*r.w;
            float4 wf = lnw4[t * 16 + aC4[j]];                     // L1-hot
            short4v s;
            s[0] = f2bfs(r.x * wf.x); s[1] = f2bfs(r.y * wf.y);
            s[2] = f2bfs(r.z * wf.z); s[3] = f2bfs(r.w * wf.w);
            *(short4v*)&Ab[aOff[j]] = s;
        }
#pragma unroll
        for (int j = 0; j < 4; ++j) *(short8*)&Bb[bOff[j]] = rb[j];
        __syncthreads();                       // single barrier per tile
        if (t < NT - 1) {                      // prefetch t+1 under MFMA phase
#pragma unroll
            for (int j = 0; j < 4; ++j) rax[j] = gAx[j][(t + 1) * 16];
#pragma unroll
            for (int j = 0; j < 4; ++j) rb[j] = gB[j][(t + 1) * 8];
        }
#pragma unroll
        for (int kk = 0; kk < 2; ++kk) {
            short8 a[2], b[4];
#pragma unroll
            for (int m = 0; m < 2; ++m)
                a[m] = *(const short8*)&Ab[(wr * 32 + m * 16 + lr) * LDP + kk * 32 + kh * 8];
#pragma unroll
            for (int n = 0; n < 4; ++n)
                b[n] = *(const short8*)&Bb[(wc * 64 + n * 16 + lr) * LDP + kk * 32 + kh * 8];
#pragma unroll
            for (int m = 0; m < 2; ++m)
#pragma unroll
                for (int n = 0; n < 4; ++n)
                    acc[m][n] = __builtin_amdgcn_mfma_f32_16x16x32_bf16(a[m], b[n], acc[m][n], 0, 0, 0);
        }
    }

    // row stats: 16 consecutive lanes share a row
#pragma unroll
    for (int j = 0; j < 4; ++j) {
#pragma unroll
        for (int m = 1; m < 16; m <<= 1) {
            sa1[j] += __shfl_xor(sa1[j], m);
            sa2[j] += __shfl_xor(sa2[j], m);
        }
        if ((tid & 15) == 0) { s_s1[aRow[j]] = sa1[j]; s_s2[aRow[j]] = sa2[j]; }
    }
    __syncthreads();
    if (tid < BM) {
        float mu = s_s1[tid] * (1.0f / ND);
        float var = s_s2[tid] * (1.0f / ND) - mu * mu;
        float rs = rsqrtf(var + 1e-5f);
        s_rs[tid] = rs;
        alpha[bm0 + tid] = mu * rs;
    }
    __syncthreads();

    // epilogue: V' = rstd*y, staged to LDS for coalesced bf16 stores
    unsigned short* Cs = (unsigned short*)As;   // 64*TLP*2B = 16.9 KB
#pragma unroll
    for (int m = 0; m < 2; ++m)
#pragma unroll
        for (int n = 0; n < 4; ++n)
#pragma unroll
            for (int r = 0; r < 4; ++r) {
                const int rowl = wr * 32 + m * 16 + kh * 4 + r;
                Cs[rowl * TLP + wc * 64 + n * 16 + lr] = f2bf(s_rs[rowl] * acc[m][n][r]);
            }
    __syncthreads();
#pragma unroll
    for (int j = 0; j < 4; ++j) {
        int idx = j * 256 + tid;                // 1024 short8s = 64 rows x 16
        int row = idx >> 4, c8 = idx & 15;
        *(short8*)&V[(size_t)(bm0 + row) * ND + bn0 + c8 * 8] = *(const short8*)&Cs[row * TLP + c8 * 8];
    }
}

// K3: stream all 12 layers per (b,s) row; reconstruct v = V' + c2v - alpha*c1v;
// LN-folded logits; redundant per-thread softmax (no serial section); mix; gate.
__global__ void k_fused(const float* __restrict__ states, const unsigned short* __restrict__ V,
                        const float* __restrict__ alpha,
                        const float* __restrict__ c1v, const float* __restrict__ c2v,
                        const float* __restrict__ lnw, const float* __restrict__ lnb,
                        const float* __restrict__ gatep, float* __restrict__ out) {
    __shared__ float s_logit[12];
    __shared__ float s_part[4][ND];
    __shared__ float s_x11[ND];
    const int p = blockIdx.x;
    const int tid = threadIdx.x;
    const int lane = tid & 63;
    const int wv = tid >> 6;
    const size_t LS = (size_t)NBS * ND;
    const float* base = states + (size_t)p * ND;
    const short4v* Vp = (const short4v*)(V + (size_t)p * ND);
    const float a_p = alpha[p];

    float4 t[4];
    float red[11];
#pragma unroll
    for (int j = 0; j < 11; ++j) red[j] = 0.f;
#pragma unroll
    for (int i = 0; i < 4; ++i) {
        int idx = lane + 64 * i;
        short4v vq = Vp[idx];
        float4 c1 = ((const float4*)c1v)[idx];
        float4 c2 = ((const float4*)c2v)[idx];
        float4 v;
        v.x = bf2f(vq[0]) + c2.x - a_p * c1.x;
        v.y = bf2f(vq[1]) + c2.y - a_p * c1.y;
        v.z = bf2f(vq[2]) + c2.z - a_p * c1.z;
        v.w = bf2f(vq[3]) + c2.w - a_p * c1.w;
        float4 w = ((const float4*)lnw)[idx];
        float4 b = ((const float4*)lnb)[idx];
        float4 tt; tt.x = v.x*w.x; tt.y = v.y*w.y; tt.z = v.z*w.z; tt.w = v.w*w.w;
        t[i] = tt;
        red[9]  += tt.x + tt.y + tt.z + tt.w;
        red[10] += v.x*b.x + v.y*b.y + v.z*b.z + v.w*b.w;
    }

    float4 x[3][4];
#pragma unroll
    for (int rr = 0; rr < 3; ++rr) {
        const int l = wv + 4 * rr;
        const float4* xr = (const float4*)(base + (size_t)l * LS);
#pragma unroll
        for (int i = 0; i < 4; ++i) {
            float4 xx = xr[lane + 64 * i];
            x[rr][i] = xx;
            red[rr]     += xx.x + xx.y + xx.z + xx.w;
            red[3 + rr] += xx.x*xx.x + xx.y*xx.y + xx.z*xx.z + xx.w*xx.w;
            red[6 + rr] += xx.x*t[i].x + xx.y*t[i].y + xx.z*t[i].z + xx.w*t[i].w;
        }
    }
#pragma unroll
    for (int m = 32; m > 0; m >>= 1) {
#pragma unroll
        for (int j = 0; j < 11; ++j) red[j] += __shfl_xor(red[j], m);
    }
    if (lane == 0) {
#pragma unroll
        for (int rr = 0; rr < 3; ++rr) {
            float mu = red[rr] * (1.0f / ND);
            float var = red[3 + rr] * (1.0f / ND) - mu * mu;
            float rstd = rsqrtf(var + 1e-5f);
            s_logit[wv + 4 * rr] = 0.0625f * (rstd * (red[6 + rr] - mu * red[9]) + red[10]);
        }
    }
    __syncthreads();

    // redundant per-thread softmax (deterministic; identical across threads)
    float lg[12];
#pragma unroll
    for (int l = 0; l < 12; ++l) lg[l] = s_logit[l];
    float mx = lg[0];
#pragma unroll
    for (int l = 1; l < 12; ++l) mx = fmaxf(mx, lg[l]);
    float sum = 0.f;
#pragma unroll
    for (int l = 0; l < 12; ++l) { lg[l] = expf(lg[l] - mx); sum += lg[l]; }
    const float inv = 1.0f / sum;
    const float g = 1.0f / (1.0f + expf(-gatep[0]));
    const float w0 = lg[wv] * inv, w1 = lg[wv + 4] * inv, w2 = lg[wv + 8] * inv;

#pragma unroll
    for (int i = 0; i < 4; ++i) {
        int idx = lane + 64 * i;
        float4 pm;
        pm.x = w0*x[0][i].x + w1*x[1][i].x + w2*x[2][i].x;
        pm.y = w0*x[0][i].y + w1*x[1][i].y + w2*x[2][i].y;
        pm.z = w0*x[0][i].z + w1*x[1][i].z + w2*x[2][i].z;
        pm.w = w0*x[0][i].w + w1*x[1][i].w + w2*x[2][i].w;
        ((float4*)s_part[wv])[idx] = pm;
        if (wv == 3) ((float4*)s_x11)[idx] = x[2][i];   // wv=3, rr=2 -> l=11
    }
    __syncthreads();

    float4 a0 = ((const float4*)s_part[0])[tid];
    float4 a1 = ((const float4*)s_part[1])[tid];
    float4 a2 = ((const float4*)s_part[2])[tid];
    float4 a3 = ((const float4*)s_part[3])[tid];
    float4 x11 = ((const float4*)s_x11)[tid];
    float4 o;
    o.x = g * x11.x + (1.f - g) * (a0.x + a1.x + a2.x + a3.x);
    o.y = g * x11.y + (1.f - g) * (a0.y + a1.y + a2.y + a3.y);
    o.z = g * x11.z + (1.f - g) * (a0.z + a1.z + a2.z + a3.z);
    o.w = g * x11.w + (1.f - g) * (a0.w + a1.w + a2.w + a3.w);
    ((float4*)(out + (size_t)p * ND))[tid] = o;
}

extern "C" void kernel_launch(void* const* d_in, const int* in_sizes, int n_in,
                              void* d_out, int out_size, void* d_ws, size_t ws_size,
                              hipStream_t stream) {
    (void)in_sizes; (void)n_in; (void)out_size; (void)ws_size;
    const float* states = (const float*)d_in[0];
    const float* Wq     = (const float*)d_in[1];
    const float* Wk     = (const float*)d_in[2];
    const float* lnw    = (const float*)d_in[3];
    const float* lnb    = (const float*)d_in[4];
    const float* gate   = (const float*)d_in[5];
    float* out = (float*)d_out;
    char* ws = (char*)d_ws;

    unsigned short* W2t  = (unsigned short*)(ws);                  // 2 MiB (ND x ND bf16)
    unsigned short* V    = (unsigned short*)(ws + (4u  << 20));    // 8 MiB (NBS x ND bf16)
    float*          alp  = (float*)        (ws + (13u << 20));     // 16 KiB
    float*          c1v  = (float*)        (ws + (13u << 20) + (64u << 10)); // 4 KiB
    float*          c2v  = (float*)        (ws + (13u << 20) + (128u << 10)); // 4 KiB
    const float* x11 = states + (size_t)(NL - 1) * NBS * ND;

    k_prep<<<dim3(256), dim3(256), 0, stream>>>(Wq, Wk, W2t);
    k_vgemm<<<dim3(512 + 8), dim3(256), 0, stream>>>(x11, W2t, lnw, lnb, V, alp, c1v, c2v);
    k_fused<<<dim3(NBS), dim3(256), 0, stream>>>(states, V, alp, c1v, c2v, lnw, lnb, gate, out);
}

// Round 9
// 74.598 us; speedup vs baseline: 1.3024x; 1.3024x over previous
//
#include <hip/hip_runtime.h>

#define NL 12
#define NB 2
#define NS 2048
#define ND 1024
#define NDK 256
#define NBS (NB*NS)   // 4096

typedef __attribute__((ext_vector_type(8))) short short8;
typedef __attribute__((ext_vector_type(4))) short short4v;
typedef __attribute__((ext_vector_type(4))) float floatx4;

__device__ __forceinline__ unsigned short f2bf(float f) {
    unsigned int u = __float_as_uint(f);
    u += 0x7FFFu + ((u >> 16) & 1u);
    return (unsigned short)(u >> 16);
}
__device__ __forceinline__ short f2bfs(float f) { return (short)f2bf(f); }
__device__ __forceinline__ float bf2f(short s) {
    return __uint_as_float(((unsigned int)(unsigned short)s) << 16);
}

// T0: blocks [0,4096): LayerNorm(states[11]) -> U bf16  (round-7 code)
//     blocks [4096,4224): transpose Wk/Wq (256x1024 fp32, k-major) ->
//                         WkT/WqT (1024x256 bf16, k-contiguous rows)
__global__ void k_pre(const float* __restrict__ x11,
                      const float* __restrict__ lnw, const float* __restrict__ lnb,
                      const float* __restrict__ Wq, const float* __restrict__ Wk,
                      unsigned short* __restrict__ U,
                      unsigned short* __restrict__ WqT, unsigned short* __restrict__ WkT) {
    const int tid = threadIdx.x;
    if (blockIdx.x >= NBS) {
        // transpose: one block handles 16 d-columns of one matrix
        __shared__ unsigned short T[NDK][18];   // [k][d-local], 9.2 KB
        const int tb = blockIdx.x - NBS;        // 0..127
        const float* src = (tb >> 6) ? Wq : Wk;
        unsigned short* dst = (tb >> 6) ? WqT : WkT;
        const int d0 = (tb & 63) * 16;
        const int kq = tid >> 2, quad = tid & 3;   // 64 k-rows per pass, 4 float4/row
#pragma unroll
        for (int pass = 0; pass < 4; ++pass) {
            const int k = pass * 64 + kq;
            float4 v = *(const float4*)(src + (size_t)k * ND + d0 + quad * 4);
            short4v s; s[0] = f2bfs(v.x); s[1] = f2bfs(v.y); s[2] = f2bfs(v.z); s[3] = f2bfs(v.w);
            *(short4v*)&T[k][quad * 4] = s;
        }
        __syncthreads();
        const int dl = tid >> 4, seg = tid & 15;   // 16 d-rows x 16 k-segs
        short8 o0, o1;
#pragma unroll
        for (int kk = 0; kk < 8; ++kk) o0[kk] = (short)T[seg * 16 + kk][dl];
#pragma unroll
        for (int kk = 0; kk < 8; ++kk) o1[kk] = (short)T[seg * 16 + 8 + kk][dl];
        unsigned short* orow = dst + (size_t)(d0 + dl) * NDK + seg * 16;
        *(short8*)orow = o0;
        *(short8*)(orow + 8) = o1;
        return;
    }
    __shared__ float red[8];
    const int p = blockIdx.x;
    const float4* xr = (const float4*)(x11 + (size_t)p * ND);
    float4 x = xr[tid];
    float s1 = x.x + x.y + x.z + x.w;
    float s2 = x.x*x.x + x.y*x.y + x.z*x.z + x.w*x.w;
#pragma unroll
    for (int m = 32; m > 0; m >>= 1) { s1 += __shfl_xor(s1, m); s2 += __shfl_xor(s2, m); }
    int wv = tid >> 6;
    if ((tid & 63) == 0) { red[wv] = s1; red[4 + wv] = s2; }
    __syncthreads();
    float S1 = red[0] + red[1] + red[2] + red[3];
    float S2 = red[4] + red[5] + red[6] + red[7];
    float mu = S1 * (1.0f / ND);
    float var = S2 * (1.0f / ND) - mu * mu;
    float rstd = rsqrtf(var + 1e-5f);
    float4 w = ((const float4*)lnw)[tid];
    float4 b = ((const float4*)lnb)[tid];
    ushort4 u;
    u.x = f2bf((x.x - mu) * rstd * w.x + b.x);
    u.y = f2bf((x.y - mu) * rstd * w.y + b.y);
    u.z = f2bf((x.z - mu) * rstd * w.z + b.z);
    u.w = f2bf((x.w - mu) * rstd * w.w + b.w);
    ((ushort4*)U)[(size_t)p * (ND / 4) + tid] = u;
}

// K1': W2t[i][j] = sum_k Wk[k][i]*Wq[k][j] from the TRANSPOSED bf16 copies —
// contiguous short8 fragment loads (5 vector loads per K-step vs 40 strided
// scalars in the old version). 256 blocks x 4 waves, wave = 16x64 tile.
__global__ void k_prep(const unsigned short* __restrict__ WkT,
                       const unsigned short* __restrict__ WqT,
                       unsigned short* __restrict__ W2t) {
    const int tid = threadIdx.x;
    const int lane = tid & 63, wv = tid >> 6;
    const int wid = blockIdx.x * 4 + wv;      // 0..1023
    const int tm = wid >> 4;                  // i-tile (16 rows)
    const int tnb = wid & 15;                 // j-tile (64 cols)
    const int lr = lane & 15, kh = lane >> 4;
    const short8* ap = (const short8*)(WkT + (size_t)(tm * 16 + lr) * NDK + kh * 8);
    const short8* bp[4];
#pragma unroll
    for (int c = 0; c < 4; ++c)
        bp[c] = (const short8*)(WqT + (size_t)(tnb * 64 + c * 16 + lr) * NDK + kh * 8);
    floatx4 acc[4];
#pragma unroll
    for (int c = 0; c < 4; ++c) acc[c] = (floatx4){0.f, 0.f, 0.f, 0.f};
#pragma unroll 4
    for (int kb = 0; kb < NDK / 32; ++kb) {
        short8 a = ap[kb * 4];
#pragma unroll
        for (int c = 0; c < 4; ++c) {
            short8 b = bp[c][kb * 4];
            acc[c] = __builtin_amdgcn_mfma_f32_16x16x32_bf16(a, b, acc[c], 0, 0, 0);
        }
    }
    const int orow = tm * 16 + kh * 4;
#pragma unroll
    for (int c = 0; c < 4; ++c)
#pragma unroll
        for (int r = 0; r < 4; ++r)
            W2t[(size_t)(orow + r) * ND + tnb * 64 + c * 16 + lr] = f2bf(acc[c][r]);
}

// K2: V (4096 x 1024 bf16) = U (4096 x 1024 bf16) @ W2t^T   (round-7 verbatim)
// 64x128 tile, BK=64, double-buffered LDS, ONE barrier per K-tile, XCD swizzle.
#define BM 64
#define BN 128
#define BK 64
#define LDP 72    // padded LDS row (elements)
#define TLP 132   // padded epilogue row (elements)
__global__ __launch_bounds__(256) void k_vgemm(const unsigned short* __restrict__ U,
                                               const unsigned short* __restrict__ W2t,
                                               unsigned short* __restrict__ V) {
    __shared__ unsigned short As[2][BM * LDP];   // 18.4 KB
    __shared__ unsigned short Bs[2][BN * LDP];   // 36.9 KB
    const int tid = threadIdx.x;
    const int lane = tid & 63;
    const int wv = tid >> 6;
    const int wr = wv >> 1, wc = wv & 1;
    const int lr = lane & 15, kh = lane >> 4;
    const int bid = blockIdx.x;                  // 512 blocks
    const int bm0 = ((bid & 7) + 8 * ((bid >> 3) & 7)) * BM;   // 64 m-tiles
    const int bn0 = (bid >> 6) * BN;                            // 8 n-tiles

    int aOff[2], bOff[4];
    const short8* gA[2];
    const short8* gB[4];
#pragma unroll
    for (int j = 0; j < 2; ++j) {
        int idx = j * 256 + tid;
        int row = idx >> 3, c8 = idx & 7;
        aOff[j] = row * LDP + c8 * 8;
        gA[j] = (const short8*)(U + (size_t)(bm0 + row) * ND) + c8;
    }
#pragma unroll
    for (int j = 0; j < 4; ++j) {
        int idx = j * 256 + tid;
        int row = idx >> 3, c8 = idx & 7;
        bOff[j] = row * LDP + c8 * 8;
        gB[j] = (const short8*)(W2t + (size_t)(bn0 + row) * ND) + c8;
    }

    floatx4 acc[2][4];
#pragma unroll
    for (int m = 0; m < 2; ++m)
#pragma unroll
        for (int n = 0; n < 4; ++n) acc[m][n] = (floatx4){0.f, 0.f, 0.f, 0.f};

    short8 ra[2], rb[4];
#pragma unroll
    for (int j = 0; j < 2; ++j) ra[j] = gA[j][0];
#pragma unroll
    for (int j = 0; j < 4; ++j) rb[j] = gB[j][0];

    const int NT = ND / BK;   // 16
#pragma unroll 1
    for (int t = 0; t < NT; ++t) {
        unsigned short* Ab = As[t & 1];
        unsigned short* Bb = Bs[t & 1];
#pragma unroll
        for (int j = 0; j < 2; ++j) *(short8*)&Ab[aOff[j]] = ra[j];
#pragma unroll
        for (int j = 0; j < 4; ++j) *(short8*)&Bb[bOff[j]] = rb[j];
        __syncthreads();                       // single barrier per tile
        if (t < NT - 1) {                      // prefetch t+1 (lands during MFMA phase)
#pragma unroll
            for (int j = 0; j < 2; ++j) ra[j] = gA[j][(t + 1) * 8];
#pragma unroll
            for (int j = 0; j < 4; ++j) rb[j] = gB[j][(t + 1) * 8];
        }
#pragma unroll
        for (int kk = 0; kk < 2; ++kk) {
            short8 a[2], b[4];
#pragma unroll
            for (int m = 0; m < 2; ++m)
                a[m] = *(const short8*)&Ab[(wr * 32 + m * 16 + lr) * LDP + kk * 32 + kh * 8];
#pragma unroll
            for (int n = 0; n < 4; ++n)
                b[n] = *(const short8*)&Bb[(wc * 64 + n * 16 + lr) * LDP + kk * 32 + kh * 8];
#pragma unroll
            for (int m = 0; m < 2; ++m)
#pragma unroll
                for (int n = 0; n < 4; ++n)
                    acc[m][n] = __builtin_amdgcn_mfma_f32_16x16x32_bf16(a[m], b[n], acc[m][n], 0, 0, 0);
        }
    }

    __syncthreads();
    unsigned short* Cs = (unsigned short*)As;
#pragma unroll
    for (int m = 0; m < 2; ++m)
#pragma unroll
        for (int n = 0; n < 4; ++n)
#pragma unroll
            for (int r = 0; r < 4; ++r)
                Cs[(wr * 32 + m * 16 + kh * 4 + r) * TLP + wc * 64 + n * 16 + lr] = f2bf(acc[m][n][r]);
    __syncthreads();
#pragma unroll
    for (int j = 0; j < 4; ++j) {
        int idx = j * 256 + tid;
        int row = idx >> 4, c8 = idx & 15;
        *(short8*)&V[(size_t)(bm0 + row) * ND + bn0 + c8 * 8] = *(const short8*)&Cs[row * TLP + c8 * 8];
    }
}

// K3: round-7 verbatim.
__global__ void k_fused(const float* __restrict__ states, const unsigned short* __restrict__ V,
                        const float* __restrict__ lnw, const float* __restrict__ lnb,
                        const float* __restrict__ gatep, float* __restrict__ out) {
    __shared__ float s_logit[12];
    __shared__ float s_w12[12];
    __shared__ float s_g;
    __shared__ float s_part[4][ND];
    __shared__ float s_x11[ND];
    const int p = blockIdx.x;
    const int tid = threadIdx.x;
    const int lane = tid & 63;
    const int wv = tid >> 6;
    const size_t LS = (size_t)NBS * ND;
    const float* base = states + (size_t)p * ND;
    const short4v* Vp = (const short4v*)(V + (size_t)p * ND);

    float4 t[4];
    float red[11];
#pragma unroll
    for (int j = 0; j < 11; ++j) red[j] = 0.f;
#pragma unroll
    for (int i = 0; i < 4; ++i) {
        int idx = lane + 64 * i;
        short4v vq = Vp[idx];
        float4 v;
        v.x = bf2f(vq[0]); v.y = bf2f(vq[1]); v.z = bf2f(vq[2]); v.w = bf2f(vq[3]);
        float4 w = ((const float4*)lnw)[idx];
        float4 b = ((const float4*)lnb)[idx];
        float4 tt; tt.x = v.x*w.x; tt.y = v.y*w.y; tt.z = v.z*w.z; tt.w = v.w*w.w;
        t[i] = tt;
        red[9]  += tt.x + tt.y + tt.z + tt.w;
        red[10] += v.x*b.x + v.y*b.y + v.z*b.z + v.w*b.w;
    }

    float4 x[3][4];
#pragma unroll
    for (int rr = 0; rr < 3; ++rr) {
        const int l = wv + 4 * rr;
        const float4* xr = (const float4*)(base + (size_t)l * LS);
#pragma unroll
        for (int i = 0; i < 4; ++i) {
            float4 xx = xr[lane + 64 * i];
            x[rr][i] = xx;
            red[rr]     += xx.x + xx.y + xx.z + xx.w;
            red[3 + rr] += xx.x*xx.x + xx.y*xx.y + xx.z*xx.z + xx.w*xx.w;
            red[6 + rr] += xx.x*t[i].x + xx.y*t[i].y + xx.z*t[i].z + xx.w*t[i].w;
        }
    }
#pragma unroll
    for (int m = 32; m > 0; m >>= 1) {
#pragma unroll
        for (int j = 0; j < 11; ++j) red[j] += __shfl_xor(red[j], m);
    }
    if (lane == 0) {
#pragma unroll
        for (int rr = 0; rr < 3; ++rr) {
            float mu = red[rr] * (1.0f / ND);
            float var = red[3 + rr] * (1.0f / ND) - mu * mu;
            float rstd = rsqrtf(var + 1e-5f);
            s_logit[wv + 4 * rr] = 0.0625f * (rstd * (red[6 + rr] - mu * red[9]) + red[10]);
        }
    }
    __syncthreads();
    if (tid == 0) {
        float mx = s_logit[0];
#pragma unroll
        for (int l = 1; l < 12; ++l) mx = fmaxf(mx, s_logit[l]);
        float e[12], sum = 0.f;
#pragma unroll
        for (int l = 0; l < 12; ++l) { e[l] = expf(s_logit[l] - mx); sum += e[l]; }
        float inv = 1.0f / sum;
#pragma unroll
        for (int l = 0; l < 12; ++l) s_w12[l] = e[l] * inv;
        s_g = 1.0f / (1.0f + expf(-gatep[0]));
    }
    __syncthreads();

    const float w0 = s_w12[wv], w1 = s_w12[wv + 4], w2 = s_w12[wv + 8];
#pragma unroll
    for (int i = 0; i < 4; ++i) {
        int idx = lane + 64 * i;
        float4 pm;
        pm.x = w0*x[0][i].x + w1*x[1][i].x + w2*x[2][i].x;
        pm.y = w0*x[0][i].y + w1*x[1][i].y + w2*x[2][i].y;
        pm.z = w0*x[0][i].z + w1*x[1][i].z + w2*x[2][i].z;
        pm.w = w0*x[0][i].w + w1*x[1][i].w + w2*x[2][i].w;
        ((float4*)s_part[wv])[idx] = pm;
        if (wv == 3) ((float4*)s_x11)[idx] = x[2][i];   // wv=3, rr=2 -> l=11
    }
    __syncthreads();

    const float g = s_g;
    float4 a0 = ((const float4*)s_part[0])[tid];
    float4 a1 = ((const float4*)s_part[1])[tid];
    float4 a2 = ((const float4*)s_part[2])[tid];
    float4 a3 = ((const float4*)s_part[3])[tid];
    float4 x11 = ((const float4*)s_x11)[tid];
    float4 o;
    o.x = g * x11.x + (1.f - g) * (a0.x + a1.x + a2.x + a3.x);
    o.y = g * x11.y + (1.f - g) * (a0.y + a1.y + a2.y + a3.y);
    o.z = g * x11.z + (1.f - g) * (a0.z + a1.z + a2.z + a3.z);
    o.w = g * x11.w + (1.f - g) * (a0.w + a1.w + a2.w + a3.w);
    ((float4*)(out + (size_t)p * ND))[tid] = o;
}

extern "C" void kernel_launch(void* const* d_in, const int* in_sizes, int n_in,
                              void* d_out, int out_size, void* d_ws, size_t ws_size,
                              hipStream_t stream) {
    (void)in_sizes; (void)n_in; (void)out_size; (void)ws_size;
    const float* states = (const float*)d_in[0];
    const float* Wq     = (const float*)d_in[1];
    const float* Wk     = (const float*)d_in[2];
    const float* lnw    = (const float*)d_in[3];
    const float* lnb    = (const float*)d_in[4];
    const float* gate   = (const float*)d_in[5];
    float* out = (float*)d_out;
    char* ws = (char*)d_ws;

    unsigned short* U   = (unsigned short*)(ws);                 // 8 MiB  (NBS x ND bf16)
    unsigned short* W2t = (unsigned short*)(ws + (9u  << 20));   // 2 MiB  (ND x ND bf16)
    unsigned short* V   = (unsigned short*)(ws + (12u << 20));   // 8 MiB  (NBS x ND bf16)
    unsigned short* WkT = (unsigned short*)(ws + (21u << 20));   // 512 KiB (ND x NDK bf16)
    unsigned short* WqT = (unsigned short*)(ws + (21u << 20) + (1u << 19)); // 512 KiB
    const float* x11 = states + (size_t)(NL - 1) * NBS * ND;

    k_pre<<<dim3(NBS + 128), dim3(256), 0, stream>>>(x11, lnw, lnb, Wq, Wk, U, WqT, WkT);
    k_prep<<<dim3(256), dim3(256), 0, stream>>>(WkT, WqT, W2t);
    k_vgemm<<<dim3((NBS / BM) * (ND / BN)), dim3(256), 0, stream>>>(U, W2t, V);
    k_fused<<<dim3(NBS), dim3(256), 0, stream>>>(states, V, lnw, lnb, gate, out);
}